// Round 18
// baseline (263.244 us; speedup 1.0000x reference)
//
#include <hip/hip_runtime.h>
#include <hip/hip_bf16.h>

#define HH 96
#define WW 96
#define NPX 9216          // HH*WW
#define NC 21             // classes

#define CH 256
#define JBX 36
#define NT 2
#define TROW 264
// prestaged path: 36 chunks of 256 i, LDS-staged (32 KB), 4 blocks/CU
#define NCHK2 36
#define K1BIL2 (JBX*NCHK2) // 1296 bilateral blocks
#define CVBLK 189          // conv blocks appended
#define RED 756            // reduce blocks in k2
// fallback path (atomics, self-staging)
#define NCHK 36

// rowsum tiling: 4 j per thread
#define RNI 144
#define RCH 64

#define RAD2 24
#define TAPS2 49

typedef __attribute__((ext_vector_type(8))) short s8v;
typedef __attribute__((ext_vector_type(16))) float f16v;

__device__ const float GN[36] = {
    6.64904e-02f, 6.55733e-02f, 6.28973e-02f, 5.86776e-02f, 5.32413e-02f,
    4.69853e-02f, 4.03286e-02f, 3.36665e-02f, 2.73351e-02f, 2.15863e-02f,
    1.65795e-02f, 1.23852e-02f, 8.99851e-03f, 6.35877e-03f, 4.37031e-03f,
    2.92139e-03f, 1.89933e-03f, 1.20102e-03f, 7.38645e-04f, 4.41830e-04f,
    2.57057e-04f, 1.45461e-04f, 8.00452e-05f, 4.28451e-05f, 2.23052e-05f,
    1.12939e-05f, 5.56182e-06f, 2.66396e-06f, 1.24101e-06f, 5.62291e-07f,
    2.47787e-07f, 1.06203e-07f, 4.42716e-08f, 1.79497e-08f, 7.07818e-09f,
    2.71479e-09f
};

__device__ __forceinline__ bool is_bf16(const void* kstd_raw){
    return (((const unsigned int*)kstd_raw)[0] & 0xFFFFu) != 0u;
}
__device__ __forceinline__ float ld_in(const void* p, int i, bool bf){
    if (bf){
        unsigned int u = ((unsigned int)((const unsigned short*)p)[i]) << 16;
        return __uint_as_float(u);
    }
    return ((const float*)p)[i];
}
__device__ __forceinline__ unsigned short f2bf(float f){
    unsigned int u = __float_as_uint(f);
    unsigned int r = u + 0x7FFFu + ((u >> 16) & 1u);   // RNE
    return (unsigned short)(r >> 16);
}
__device__ __forceinline__ float bf2float(unsigned short h){
    return __uint_as_float(((unsigned)h) << 16);
}
// permuted-k global tmp layout: row(i)*256 + c*8 + idx(i)
__device__ __forceinline__ int tmp_row(int i){
    return (i>>8)*32 + ((i>>5)&7)*4 + ((i>>4)&1)*2 + ((i>>2)&1);
}
__device__ __forceinline__ int tmp_idx(int i){
    return (i&3) | ((i>>1)&4);
}

// ---------- setup: features, U, q0, and prestaged A/B channel fragments ----------
__global__ __launch_bounds__(64) void setup_kernel(const void* __restrict__ unary_raw,
                                                   const void* __restrict__ ref_raw,
                                                   const void* __restrict__ kstd_raw,
                                                   float* __restrict__ feat,
                                                   float* __restrict__ U, float* __restrict__ q,
                                                   float* __restrict__ qbf,
                                                   float* __restrict__ nacc,
                                                   unsigned short* __restrict__ featA_g,
                                                   unsigned short* __restrict__ bfrag_g,
                                                   int use_part){
    int i = blockIdx.x*64 + threadIdx.x;
    if (i >= NPX) return;
    bool bf = is_bf16(kstd_raw);
    const float SCL = 0.84932180028801907f; // sqrt(0.5*log2(e))
    int y = i / WW, x = i - y*WW;
    float f0 = (float)y * (SCL / ld_in(kstd_raw, 0, bf));
    float f1 = (float)x * (SCL / ld_in(kstd_raw, 1, bf));
    float f2 = ld_in(ref_raw, 0*NPX+i, bf) * (SCL / ld_in(kstd_raw, 2, bf));
    float f3 = ld_in(ref_raw, 1*NPX+i, bf) * (SCL / ld_in(kstd_raw, 3, bf));
    float f4 = ld_in(ref_raw, 2*NPX+i, bf) * (SCL / ld_in(kstd_raw, 4, bf));
    float sq = f0*f0 + f1*f1 + f2*f2 + f3*f3 + f4*f4;
    feat[i*8+0] = f0; feat[i*8+1] = f1; feat[i*8+2] = f2; feat[i*8+3] = f3; feat[i*8+4] = f4;
    feat[i*8+5] = sq;
    feat[i*8+6] = 0.f; feat[i*8+7] = 0.f;
    nacc[i] = 0.f;

    if (use_part){
        float f[5] = {f0, f1, f2, f3, f4};
        unsigned short ach[32], bch[32];
        #pragma unroll
        for (int d = 0; d < 5; ++d){
            unsigned short h = f2bf(f[d]);
            float hf = bf2float(h);
            unsigned short l = f2bf(f[d] - hf);
            float lf = bf2float(l);
            unsigned short h2 = f2bf(2.f*hf);
            unsigned short l2 = f2bf(2.f*lf);
            ach[4*d+0]=h2; ach[4*d+1]=h2; ach[4*d+2]=l2; ach[4*d+3]=l2;
            bch[4*d+0]=h;  bch[4*d+1]=l;  bch[4*d+2]=h;  bch[4*d+3]=l;
        }
        unsigned short s1 = f2bf(sq); float s1f = bf2float(s1);
        unsigned short s2 = f2bf(sq - s1f); float s2f = bf2float(s2);
        unsigned short s3 = f2bf(sq - s1f - s2f);
        ach[20] = (unsigned short)(s1 ^ 0x8000u);
        ach[21] = (unsigned short)(s2 ^ 0x8000u);
        ach[22] = (unsigned short)(s3 ^ 0x8000u);
        ach[23] = 0x3F80u; ach[24] = 0x3F80u; ach[25] = 0x3F80u;
        bch[20] = 0x3F80u; bch[21] = 0x3F80u; bch[22] = 0x3F80u;
        bch[23] = (unsigned short)(s1 ^ 0x8000u);
        bch[24] = (unsigned short)(s2 ^ 0x8000u);
        bch[25] = (unsigned short)(s3 ^ 0x8000u);
        #pragma unroll
        for (int k = 26; k < 32; ++k){ ach[k] = 0; bch[k] = 0; }
        #pragma unroll
        for (int ko = 0; ko < 4; ++ko){
            s8v va, vb;
            #pragma unroll
            for (int t = 0; t < 8; ++t){ va[t] = (short)ach[ko*8+t]; vb[t] = (short)bch[ko*8+t]; }
            *(s8v*)(featA_g + ((size_t)ko*NPX + i)*8) = va;
            *(s8v*)(bfrag_g + (size_t)i*32 + ko*8) = vb;
        }
    }

    float u[NC]; float m = -1e30f;
    #pragma unroll
    for (int c = 0; c < NC; ++c){
        float v = ld_in(unary_raw, c*NPX+i, bf);
        v = fminf(fmaxf(v, 1e-5f), 1.0f);
        float lg = logf(v);
        U[c*NPX+i] = lg;
        u[c] = lg;
        m = fmaxf(m, lg);
        if (!use_part) qbf[c*NPX+i] = 0.f;
    }
    float s = 0.f;
    #pragma unroll
    for (int c = 0; c < NC; ++c){ u[c] = expf(u[c]-m); s += u[c]; }
    float inv = 1.f/s;
    #pragma unroll
    for (int c = 0; c < NC; ++c) q[c*NPX+i] = u[c]*inv;
}

// ---------- rowsum of K, 4 j per thread ----------
__global__ __launch_bounds__(256) void rowsum_kernel(const float* __restrict__ feat,
                                                     float* __restrict__ nacc){
    __shared__ __align__(16) float s_feat[RNI*8];
    int tid = threadIdx.x;
    int i0 = blockIdx.y * RNI;
    for (int s = tid; s < RNI*8; s += 256){
        float v = feat[i0*8 + s];
        int sl = s & 7;
        if (sl < 5) v *= 2.0f;
        else if (sl == 5) v = -v;
        s_feat[s] = v;
    }
    __syncthreads();
    int jb0 = blockIdx.x*1024 + tid;
    float4 fj[4]; float fj4[4], nsqj[4];
    float a[4] = {0.f, 0.f, 0.f, 0.f};
    #pragma unroll
    for (int jb = 0; jb < 4; ++jb){
        int j = jb0 + jb*256;
        fj[jb] = *(const float4*)(feat + j*8);
        float2 t = *(const float2*)(feat + j*8 + 4);
        fj4[jb] = t.x; nsqj[jb] = -t.y;
    }
    #pragma unroll 2
    for (int ii = 0; ii < RNI; ++ii){
        const float* sf = s_feat + ii*8;
        float4 f0 = *(const float4*)sf;
        float2 f45 = *(const float2*)(sf+4);
        #pragma unroll
        for (int jb = 0; jb < 4; ++jb){
            float t = nsqj[jb] + f45.y;
            t = fmaf(fj[jb].x, f0.x, t); t = fmaf(fj[jb].y, f0.y, t);
            t = fmaf(fj[jb].z, f0.z, t); t = fmaf(fj[jb].w, f0.w, t);
            t = fmaf(fj4[jb], f45.x, t);
            a[jb] += __builtin_amdgcn_exp2f(t);
        }
    }
    #pragma unroll
    for (int jb = 0; jb < 4; ++jb) atomicAdd(&nacc[jb0 + jb*256], a[jb]);
}

// ---------- normfin + initial tmpA production (iter 0) ----------
__global__ __launch_bounds__(64) void normfin_kernel(const float* __restrict__ nacc,
                                                     float* __restrict__ rnorm,
                                                     const float* __restrict__ q,
                                                     unsigned short* __restrict__ tmpA_g,
                                                     int use_part){
    int j = blockIdx.x*64 + threadIdx.x;
    if (j >= NPX) return;
    float rn = 1.0f / (sqrtf(nacc[j]) + 1e-8f);
    rnorm[j] = rn;
    if (use_part){
        int row = tmp_row(j), idx = tmp_idx(j);
        unsigned short* base = tmpA_g + (size_t)row*256 + idx;
        #pragma unroll
        for (int c = 0; c < NC; ++c)
            base[c*8] = f2bf(q[c*NPX+j] * rn);
        #pragma unroll
        for (int c = NC; c < 32; ++c)
            base[c*8] = 0;
    }
}

// ---------- standalone convs (fallback path only) ----------
__global__ __launch_bounds__(256) void convh_kernel(const float* __restrict__ q,
                                                    float* __restrict__ o){
    int gid = blockIdx.x*256 + threadIdx.x;
    int c   = gid / 2304;
    int rem = gid - c*2304;
    int y   = rem / 24;
    int x0  = (rem - y*24) * 4;
    const float* row = q + c*NPX + y*WW;
    float a0 = 0.f, a1 = 0.f, a2 = 0.f, a3 = 0.f;
    #pragma unroll
    for (int t = 0; t < 52; ++t){
        int xx = x0 + t - RAD2;
        int xc = min(max(xx, 0), WW-1);
        float v = row[xc];
        v = ((unsigned)xx < (unsigned)WW) ? v : 0.f;
        if (t <= 48)           a0 = fmaf(GN[abs(t     - RAD2)], v, a0);
        if (t >= 1 && t <= 49) a1 = fmaf(GN[abs(t - 1 - RAD2)], v, a1);
        if (t >= 2 && t <= 50) a2 = fmaf(GN[abs(t - 2 - RAD2)], v, a2);
        if (t >= 3)            a3 = fmaf(GN[abs(t - 3 - RAD2)], v, a3);
    }
    float* op = o + c*NPX + y*WW + x0;
    op[0] = a0; op[1] = a1; op[2] = a2; op[3] = a3;
}

__global__ __launch_bounds__(256) void convv_kernel(const float* __restrict__ q,
                                                    float* __restrict__ o){
    int gid = blockIdx.x*256 + threadIdx.x;
    int c   = gid / 2304;
    int rem = gid - c*2304;
    int x   = rem % WW;
    int y0  = (rem / WW) * 4;
    const float* col = q + c*NPX + x;
    float a0 = 0.f, a1 = 0.f, a2 = 0.f, a3 = 0.f;
    #pragma unroll
    for (int t = 0; t < 52; ++t){
        int yy = y0 + t - RAD2;
        int yc = min(max(yy, 0), HH-1);
        float v = col[yc*WW];
        v = ((unsigned)yy < (unsigned)HH) ? v : 0.f;
        if (t <= 48)           a0 = fmaf(GN[abs(t     - RAD2)], v, a0);
        if (t >= 1 && t <= 49) a1 = fmaf(GN[abs(t - 1 - RAD2)], v, a1);
        if (t >= 2 && t <= 50) a2 = fmaf(GN[abs(t - 2 - RAD2)], v, a2);
        if (t >= 3)            a3 = fmaf(GN[abs(t - 3 - RAD2)], v, a3);
    }
    float* op = o + c*NPX + x;
    op[(y0+0)*WW] = a0; op[(y0+1)*WW] = a1; op[(y0+2)*WW] = a2; op[(y0+3)*WW] = a3;
}

// ---------- K1 (prestaged + 32 KB LDS, 4 blocks/CU): 256-i chunks + convv branch ----------
__global__ __launch_bounds__(256, 4) void k1_pre_kernel(const float* __restrict__ q,
                                                        const unsigned short* __restrict__ featA_g,
                                                        const unsigned short* __restrict__ bfrag_g,
                                                        const unsigned short* __restrict__ tmpA_g,
                                                        float* __restrict__ part,
                                                        float* __restrict__ t1b){
    __shared__ __align__(16) unsigned short s_feat[4*256*8];  // 16 KB
    __shared__ __align__(16) unsigned short s_tmp[32*256];    // 16 KB
    int tid = threadIdx.x;

    if (blockIdx.x >= K1BIL2){
        // vertical conv FIRST (order swap exact for zero-padded separable conv)
        int gid = (blockIdx.x - K1BIL2)*256 + tid;
        int c   = gid / 2304;
        int rem = gid - c*2304;
        int x   = rem % WW;
        int y0  = (rem / WW) * 4;
        const float* col = q + c*NPX + x;
        float a0 = 0.f, a1 = 0.f, a2 = 0.f, a3 = 0.f;
        #pragma unroll
        for (int t = 0; t < 52; ++t){
            int yy = y0 + t - RAD2;
            int yc = min(max(yy, 0), HH-1);
            float v = col[yc*WW];
            v = ((unsigned)yy < (unsigned)HH) ? v : 0.f;
            if (t <= 48)           a0 = fmaf(GN[abs(t     - RAD2)], v, a0);
            if (t >= 1 && t <= 49) a1 = fmaf(GN[abs(t - 1 - RAD2)], v, a1);
            if (t >= 2 && t <= 50) a2 = fmaf(GN[abs(t - 2 - RAD2)], v, a2);
            if (t >= 3)            a3 = fmaf(GN[abs(t - 3 - RAD2)], v, a3);
        }
        float* op = t1b + c*NPX + x;
        op[(y0+0)*WW] = a0; op[(y0+1)*WW] = a1; op[(y0+2)*WW] = a2; op[(y0+3)*WW] = a3;
        return;
    }

    int jb = blockIdx.x % JBX;
    int chunk = blockIdx.x / JBX;      // 0..35, each covers 256 i
    int i0 = chunk * CH;

    // ---- stage chunk fragments into LDS (pure copy, 32 KB total) ----
    #pragma unroll
    for (int r = 0; r < 4; ++r){
        int e = r*256 + tid;           // 0..1023
        int ko = e >> 8, il = e & 255;
        *(s8v*)(s_feat + (size_t)e*8) =
            *(const s8v*)(featA_g + ((size_t)ko*NPX + i0 + il)*8);
    }
    #pragma unroll
    for (int r = 0; r < 4; ++r){
        int e = r*256 + tid;           // 0..1023
        *(s8v*)(s_tmp + (size_t)e*8) =
            *(const s8v*)(tmpA_g + (size_t)(i0/8)*256 + (size_t)e*8);
    }

    int lane = tid & 63;
    int wv = tid >> 6;
    int half = lane >> 5;
    int jl = lane & 31;
    int jwb = jb*256 + wv*64;

    s8v bf0[NT], bf1[NT];
    #pragma unroll
    for (int n = 0; n < NT; ++n){
        size_t jj = (size_t)(jwb + n*32 + jl)*32;
        bf0[n] = *(const s8v*)(bfrag_g + jj + half*8);
        bf1[n] = *(const s8v*)(bfrag_g + jj + (2+half)*8);
    }

    f16v zf;
    #pragma unroll
    for (int r = 0; r < 16; ++r) zf[r] = 0.f;
    f16v acc[NT];
    #pragma unroll
    for (int n = 0; n < NT; ++n) acc[n] = zf;

    __syncthreads();

    for (int b = 0; b < 8; ++b){
        s8v af0 = *(const s8v*)(s_feat + ((size_t)half*256     + b*32 + jl)*8);
        s8v af1 = *(const s8v*)(s_feat + ((size_t)(2+half)*256 + b*32 + jl)*8);
        s8v at0 = *(const s8v*)(s_tmp + (size_t)(b*4 +     half)*256 + jl*8);
        s8v at1 = *(const s8v*)(s_tmp + (size_t)(b*4 + 2 + half)*256 + jl*8);
        #pragma unroll
        for (int n = 0; n < NT; ++n){
            f16v c1 = __builtin_amdgcn_mfma_f32_32x32x16_bf16(af0, bf0[n], zf, 0, 0, 0);
            c1 = __builtin_amdgcn_mfma_f32_32x32x16_bf16(af1, bf1[n], c1, 0, 0, 0);
            union { s8v v; unsigned u[4]; } w1f, w2f;
            #pragma unroll
            for (int p = 0; p < 4; ++p){
                float e0 = __builtin_amdgcn_exp2f(c1[2*p]);
                float e1 = __builtin_amdgcn_exp2f(c1[2*p+1]);
                union { __hip_bfloat162 h2; unsigned uu; } pk;
                pk.h2 = __float22bfloat162_rn(make_float2(e0, e1));
                w1f.u[p] = pk.uu;
                float e2 = __builtin_amdgcn_exp2f(c1[8+2*p]);
                float e3 = __builtin_amdgcn_exp2f(c1[8+2*p+1]);
                pk.h2 = __float22bfloat162_rn(make_float2(e2, e3));
                w2f.u[p] = pk.uu;
            }
            acc[n] = __builtin_amdgcn_mfma_f32_32x32x16_bf16(at0, w1f.v, acc[n], 0, 0, 0);
            acc[n] = __builtin_amdgcn_mfma_f32_32x32x16_bf16(at1, w2f.v, acc[n], 0, 0, 0);
        }
    }
    float* dst = part + (size_t)chunk * (NC*NPX);
    #pragma unroll
    for (int n = 0; n < NT; ++n){
        int j = jwb + n*32 + jl;
        #pragma unroll
        for (int r = 0; r < 16; ++r){
            int c = (r&3) + 8*(r>>2) + 4*half;
            if (c < NC) dst[c*NPX + j] = acc[n][r];
        }
    }
}

// ---------- K1 fallback (atomic path, self-staging, 256-i chunks) ----------
__global__ __launch_bounds__(256, 4) void k1_kernel(const float* __restrict__ q,
                                                    const float* __restrict__ feat,
                                                    const float* __restrict__ rnorm,
                                                    float* __restrict__ qbf){
    __shared__ __align__(16) unsigned short s_featA[4*CH*8];
    __shared__ __align__(16) unsigned short s_tmpA[(CH/8)*TROW];
    int tid = threadIdx.x;
    int jb = blockIdx.x % JBX;
    int chunk = blockIdx.x / JBX;
    int i0 = chunk * CH;

    {
        const float* fp = feat + (size_t)(i0+tid)*8;
        float4 f03 = *(const float4*)fp; float2 f45 = *(const float2*)(fp+4);
        float f[5] = {f03.x, f03.y, f03.z, f03.w, f45.x};
        float sq = f45.y;
        unsigned short ach[32];
        #pragma unroll
        for (int d = 0; d < 5; ++d){
            unsigned short h = f2bf(f[d]);
            float hf = bf2float(h);
            unsigned short l = f2bf(f[d] - hf);
            float lf = bf2float(l);
            unsigned short h2 = f2bf(2.f*hf);
            unsigned short l2 = f2bf(2.f*lf);
            ach[4*d+0]=h2; ach[4*d+1]=h2; ach[4*d+2]=l2; ach[4*d+3]=l2;
        }
        unsigned short s1 = f2bf(sq); float s1f = bf2float(s1);
        unsigned short s2 = f2bf(sq - s1f); float s2f = bf2float(s2);
        unsigned short s3 = f2bf(sq - s1f - s2f);
        ach[20] = (unsigned short)(s1 ^ 0x8000u);
        ach[21] = (unsigned short)(s2 ^ 0x8000u);
        ach[22] = (unsigned short)(s3 ^ 0x8000u);
        ach[23] = 0x3F80u; ach[24] = 0x3F80u; ach[25] = 0x3F80u;
        #pragma unroll
        for (int k = 26; k < 32; ++k) ach[k] = 0;
        #pragma unroll
        for (int ko = 0; ko < 4; ++ko){
            s8v v;
            #pragma unroll
            for (int t = 0; t < 8; ++t) v[t] = (short)ach[ko*8+t];
            *(s8v*)(s_featA + (ko*CH + tid)*8) = v;
        }
    }
    for (int e = tid; e < 32*CH; e += 256){
        int c = e >> 8;
        int i = e & (CH-1);
        float val = (c < NC) ? q[c*NPX + i0 + i] * rnorm[i0 + i] : 0.f;
        int b = i >> 5, L = i & 31;
        int row = b*4 + ((L>>4)&1)*2 + ((L>>2)&1);
        int idx = (L&3) | ((L>>1)&4);
        s_tmpA[row*TROW + c*8 + idx] = f2bf(val);
    }

    int lane = tid & 63;
    int wv = tid >> 6;
    int half = lane >> 5;
    int jl = lane & 31;
    int jwb = jb*256 + wv*64;

    s8v bf0[NT], bf1[NT];
    #pragma unroll
    for (int n = 0; n < NT; ++n){
        const float* fp = feat + (size_t)(jwb + n*32 + jl)*8;
        float4 f03 = *(const float4*)fp; float2 f45 = *(const float2*)(fp+4);
        float f[5] = {f03.x, f03.y, f03.z, f03.w, f45.x};
        float sq = f45.y;
        unsigned short bch[32];
        #pragma unroll
        for (int d = 0; d < 5; ++d){
            unsigned short h = f2bf(f[d]);
            float hf = bf2float(h);
            unsigned short l = f2bf(f[d] - hf);
            bch[4*d+0]=h; bch[4*d+1]=l; bch[4*d+2]=h; bch[4*d+3]=l;
        }
        unsigned short s1 = f2bf(sq); float s1f = bf2float(s1);
        unsigned short s2 = f2bf(sq - s1f); float s2f = bf2float(s2);
        unsigned short s3 = f2bf(sq - s1f - s2f);
        bch[20] = 0x3F80u; bch[21] = 0x3F80u; bch[22] = 0x3F80u;
        bch[23] = (unsigned short)(s1 ^ 0x8000u);
        bch[24] = (unsigned short)(s2 ^ 0x8000u);
        bch[25] = (unsigned short)(s3 ^ 0x8000u);
        #pragma unroll
        for (int k = 26; k < 32; ++k) bch[k] = 0;
        #pragma unroll
        for (int t = 0; t < 8; ++t){
            bf0[n][t] = (short)(half ? bch[8+t]  : bch[t]);
            bf1[n][t] = (short)(half ? bch[24+t] : bch[16+t]);
        }
    }

    f16v zf;
    #pragma unroll
    for (int r = 0; r < 16; ++r) zf[r] = 0.f;
    f16v acc[NT];
    #pragma unroll
    for (int n = 0; n < NT; ++n) acc[n] = zf;

    __syncthreads();

    for (int b = 0; b < 8; ++b){
        s8v af0 = *(const s8v*)(s_featA + (((0+half)*CH + b*32 + jl))*8);
        s8v af1 = *(const s8v*)(s_featA + (((2+half)*CH + b*32 + jl))*8);
        s8v at0 = *(const s8v*)(s_tmpA + (b*4 +     half)*TROW + jl*8);
        s8v at1 = *(const s8v*)(s_tmpA + (b*4 + 2 + half)*TROW + jl*8);
        #pragma unroll
        for (int n = 0; n < NT; ++n){
            f16v c1 = __builtin_amdgcn_mfma_f32_32x32x16_bf16(af0, bf0[n], zf, 0, 0, 0);
            c1 = __builtin_amdgcn_mfma_f32_32x32x16_bf16(af1, bf1[n], c1, 0, 0, 0);
            union { s8v v; unsigned u[4]; } w1f, w2f;
            #pragma unroll
            for (int p = 0; p < 4; ++p){
                float e0 = __builtin_amdgcn_exp2f(c1[2*p]);
                float e1 = __builtin_amdgcn_exp2f(c1[2*p+1]);
                union { __hip_bfloat162 h2; unsigned uu; } pk;
                pk.h2 = __float22bfloat162_rn(make_float2(e0, e1));
                w1f.u[p] = pk.uu;
                float e2 = __builtin_amdgcn_exp2f(c1[8+2*p]);
                float e3 = __builtin_amdgcn_exp2f(c1[8+2*p+1]);
                pk.h2 = __float22bfloat162_rn(make_float2(e2, e3));
                w2f.u[p] = pk.uu;
            }
            acc[n] = __builtin_amdgcn_mfma_f32_32x32x16_bf16(at0, w1f.v, acc[n], 0, 0, 0);
            acc[n] = __builtin_amdgcn_mfma_f32_32x32x16_bf16(at1, w2f.v, acc[n], 0, 0, 0);
        }
    }
    #pragma unroll
    for (int n = 0; n < NT; ++n){
        int j = jwb + n*32 + jl;
        #pragma unroll
        for (int r = 0; r < 16; ++r){
            int c = (r&3) + 8*(r>>2) + 4*half;
            if (c < NC) atomicAdd(&qbf[c*NPX + j], acc[n][r]);
        }
    }
}

// ---------- K2: wide reduce (36 partials) + horizontal conv appended ----------
__global__ __launch_bounds__(256) void k2_kernel(const float* __restrict__ part,
                                                 float* __restrict__ qbf,
                                                 const float* __restrict__ t1b,
                                                 float* __restrict__ qsf){
    int bx = blockIdx.x;
    int tid = threadIdx.x;
    if (bx < RED){
        int idx = bx*256 + tid;
        float s = 0.f;
        #pragma unroll
        for (int ch = 0; ch < NCHK2; ++ch) s += part[(size_t)ch*(NC*NPX) + idx];
        qbf[idx] = s;
        return;
    }
    int gid = (bx - RED)*256 + tid;
    int c   = gid / 2304;
    int rem = gid - c*2304;
    int y   = rem / 24;
    int x0  = (rem - y*24) * 4;
    const float* row = t1b + c*NPX + y*WW;
    float a0 = 0.f, a1 = 0.f, a2 = 0.f, a3 = 0.f;
    #pragma unroll
    for (int t = 0; t < 52; ++t){
        int xx = x0 + t - RAD2;
        int xc = min(max(xx, 0), WW-1);
        float v = row[xc];
        v = ((unsigned)xx < (unsigned)WW) ? v : 0.f;
        if (t <= 48)           a0 = fmaf(GN[abs(t     - RAD2)], v, a0);
        if (t >= 1 && t <= 49) a1 = fmaf(GN[abs(t - 1 - RAD2)], v, a1);
        if (t >= 2 && t <= 50) a2 = fmaf(GN[abs(t - 2 - RAD2)], v, a2);
        if (t >= 3)            a3 = fmaf(GN[abs(t - 3 - RAD2)], v, a3);
    }
    float* op = qsf + c*NPX + y*WW + x0;
    op[0] = a0; op[1] = a1; op[2] = a2; op[3] = a3;
}

// ---------- K3: combine + produce next iteration's tmpA ----------
__global__ __launch_bounds__(64) void combine_kernel(const float* __restrict__ U,
                                                     float* __restrict__ qbf,
                                                     const float* __restrict__ qsf,
                                                     const float* __restrict__ rnorm,
                                                     float* __restrict__ qn,
                                                     unsigned short* __restrict__ tmpA_g,
                                                     void* __restrict__ outp,
                                                     const void* __restrict__ kstd_raw,
                                                     int use_part){
    int j = blockIdx.x*64 + threadIdx.x;
    if (j >= NPX) return;
    float rn = rnorm[j];
    float rn4 = 4.0f * rn;
    float h[NC]; float m = -1e30f;
    #pragma unroll
    for (int c = 0; c < NC; ++c){
        float b = qbf[c*NPX+j];
        if (!use_part) qbf[c*NPX+j] = 0.f;
        float v = U[c*NPX+j] + b*rn4 + 2.0f*qsf[c*NPX+j];
        h[c] = v; m = fmaxf(m, v);
    }
    float s = 0.f;
    #pragma unroll
    for (int c = 0; c < NC; ++c){ h[c] = expf(h[c]-m); s += h[c]; }
    float inv = 1.f/s;
    bool bf = outp ? is_bf16(kstd_raw) : false;
    int row = tmp_row(j), idx = tmp_idx(j);
    unsigned short* base = use_part ? (tmpA_g + (size_t)row*256 + idx) : nullptr;
    #pragma unroll
    for (int c = 0; c < NC; ++c){
        float v = h[c]*inv;
        qn[c*NPX+j] = v;
        if (base) base[c*8] = f2bf(v * rn);
        if (outp){
            if (bf) ((__hip_bfloat16*)outp)[c*NPX+j] = __float2bfloat16(v);
            else    ((float*)outp)[c*NPX+j] = v;
        }
    }
}

extern "C" void kernel_launch(void* const* d_in, const int* in_sizes, int n_in,
                              void* d_out, int out_size, void* d_ws, size_t ws_size,
                              hipStream_t stream) {
    const void* unary_raw = d_in[0];
    const void* ref_raw   = d_in[1];
    const void* kstd_raw  = d_in[2];

    float* w = (float*)d_ws;
    float* feat  = w; w += NPX*8;
    float* U     = w; w += NC*NPX;
    float* qA    = w; w += NC*NPX;
    float* qB    = w; w += NC*NPX;
    float* t1b   = w; w += NC*NPX;
    float* qsf   = w; w += NC*NPX;
    float* qbf   = w; w += NC*NPX;
    float* nacc  = w; w += NPX;
    float* rnorm = w; w += NPX;
    unsigned short* featA_g = (unsigned short*)w; w += (size_t)4*NPX*8/2;
    unsigned short* bfrag_g = (unsigned short*)w; w += (size_t)NPX*32/2;
    unsigned short* tmpA_g  = (unsigned short*)w; w += (size_t)(NPX/8)*256/2;
    float* part  = w; w += (size_t)NCHK2*NC*NPX;

    size_t need = (size_t)((char*)w - (char*)d_ws);
    int use_part = (ws_size >= need) ? 1 : 0;

    hipLaunchKernelGGL(setup_kernel, dim3(144), dim3(64), 0, stream,
                       unary_raw, ref_raw, kstd_raw, feat, U, qA, qbf, nacc,
                       featA_g, bfrag_g, use_part);
    hipLaunchKernelGGL(rowsum_kernel, dim3(9, RCH), dim3(256), 0, stream, feat, nacc);
    hipLaunchKernelGGL(normfin_kernel, dim3(144), dim3(64), 0, stream,
                       nacc, rnorm, qA, tmpA_g, use_part);

    float* qc = qA; float* qn = qB;
    for (int it = 0; it < 5; ++it){
        if (use_part){
            hipLaunchKernelGGL(k1_pre_kernel, dim3(K1BIL2 + CVBLK), dim3(256), 0, stream,
                               qc, featA_g, bfrag_g, tmpA_g, part, t1b);
            hipLaunchKernelGGL(k2_kernel, dim3(RED + CVBLK), dim3(256), 0, stream,
                               part, qbf, t1b, qsf);
        } else {
            hipLaunchKernelGGL(convh_kernel, dim3(189), dim3(256), 0, stream, qc, t1b);
            hipLaunchKernelGGL(convv_kernel, dim3(189), dim3(256), 0, stream, t1b, qsf);
            hipLaunchKernelGGL(k1_kernel, dim3(JBX*NCHK), dim3(256), 0, stream,
                               qc, feat, rnorm, qbf);
        }
        hipLaunchKernelGGL(combine_kernel, dim3(144), dim3(64), 0, stream,
                           U, qbf, qsf, rnorm, qn, tmpA_g,
                           (it == 4) ? d_out : (void*)nullptr, kstd_raw, use_part);
        float* tswap = qc; qc = qn; qn = tswap;
    }
}

// Round 19
// 255.029 us; speedup vs baseline: 1.0322x; 1.0322x over previous
//
#include <hip/hip_runtime.h>
#include <hip/hip_bf16.h>

#define HH 96
#define WW 96
#define NPX 9216          // HH*WW
#define NC 21             // classes

#define CH 256
#define JBX 36
#define NT 2
#define TROW 264
// prestaged path: 18 super-chunks of 512 i, LDS-staged (64 KB), 2 blocks/CU
#define NCHK2 18
#define K1BIL2 (JBX*NCHK2) // 648 bilateral blocks
#define CVBLK 189          // conv blocks appended
#define RED 756            // reduce blocks in k2
// fallback path (atomics, self-staging)
#define NCHK 36

// rowsum tiling: 4 j per thread
#define RNI 144
#define RCH 64

#define RAD2 24
#define TAPS2 49

typedef __attribute__((ext_vector_type(8))) short s8v;
typedef __attribute__((ext_vector_type(16))) float f16v;

__device__ const float GN[36] = {
    6.64904e-02f, 6.55733e-02f, 6.28973e-02f, 5.86776e-02f, 5.32413e-02f,
    4.69853e-02f, 4.03286e-02f, 3.36665e-02f, 2.73351e-02f, 2.15863e-02f,
    1.65795e-02f, 1.23852e-02f, 8.99851e-03f, 6.35877e-03f, 4.37031e-03f,
    2.92139e-03f, 1.89933e-03f, 1.20102e-03f, 7.38645e-04f, 4.41830e-04f,
    2.57057e-04f, 1.45461e-04f, 8.00452e-05f, 4.28451e-05f, 2.23052e-05f,
    1.12939e-05f, 5.56182e-06f, 2.66396e-06f, 1.24101e-06f, 5.62291e-07f,
    2.47787e-07f, 1.06203e-07f, 4.42716e-08f, 1.79497e-08f, 7.07818e-09f,
    2.71479e-09f
};

__device__ __forceinline__ bool is_bf16(const void* kstd_raw){
    return (((const unsigned int*)kstd_raw)[0] & 0xFFFFu) != 0u;
}
__device__ __forceinline__ float ld_in(const void* p, int i, bool bf){
    if (bf){
        unsigned int u = ((unsigned int)((const unsigned short*)p)[i]) << 16;
        return __uint_as_float(u);
    }
    return ((const float*)p)[i];
}
__device__ __forceinline__ unsigned short f2bf(float f){
    unsigned int u = __float_as_uint(f);
    unsigned int r = u + 0x7FFFu + ((u >> 16) & 1u);   // RNE
    return (unsigned short)(r >> 16);
}
__device__ __forceinline__ float bf2float(unsigned short h){
    return __uint_as_float(((unsigned)h) << 16);
}
// permuted-k global tmp layout: row(i)*256 + c*8 + idx(i)
__device__ __forceinline__ int tmp_row(int i){
    return (i>>8)*32 + ((i>>5)&7)*4 + ((i>>4)&1)*2 + ((i>>2)&1);
}
__device__ __forceinline__ int tmp_idx(int i){
    return (i&3) | ((i>>1)&4);
}

// ---------- setup: features, U, q0, and prestaged A/B channel fragments ----------
__global__ __launch_bounds__(64) void setup_kernel(const void* __restrict__ unary_raw,
                                                   const void* __restrict__ ref_raw,
                                                   const void* __restrict__ kstd_raw,
                                                   float* __restrict__ feat,
                                                   float* __restrict__ U, float* __restrict__ q,
                                                   float* __restrict__ qbf,
                                                   float* __restrict__ nacc,
                                                   unsigned short* __restrict__ featA_g,
                                                   unsigned short* __restrict__ bfrag_g,
                                                   int use_part){
    int i = blockIdx.x*64 + threadIdx.x;
    if (i >= NPX) return;
    bool bf = is_bf16(kstd_raw);
    const float SCL = 0.84932180028801907f; // sqrt(0.5*log2(e))
    int y = i / WW, x = i - y*WW;
    float f0 = (float)y * (SCL / ld_in(kstd_raw, 0, bf));
    float f1 = (float)x * (SCL / ld_in(kstd_raw, 1, bf));
    float f2 = ld_in(ref_raw, 0*NPX+i, bf) * (SCL / ld_in(kstd_raw, 2, bf));
    float f3 = ld_in(ref_raw, 1*NPX+i, bf) * (SCL / ld_in(kstd_raw, 3, bf));
    float f4 = ld_in(ref_raw, 2*NPX+i, bf) * (SCL / ld_in(kstd_raw, 4, bf));
    float sq = f0*f0 + f1*f1 + f2*f2 + f3*f3 + f4*f4;
    feat[i*8+0] = f0; feat[i*8+1] = f1; feat[i*8+2] = f2; feat[i*8+3] = f3; feat[i*8+4] = f4;
    feat[i*8+5] = sq;
    feat[i*8+6] = 0.f; feat[i*8+7] = 0.f;
    nacc[i] = 0.f;

    if (use_part){
        float f[5] = {f0, f1, f2, f3, f4};
        unsigned short ach[32], bch[32];
        #pragma unroll
        for (int d = 0; d < 5; ++d){
            unsigned short h = f2bf(f[d]);
            float hf = bf2float(h);
            unsigned short l = f2bf(f[d] - hf);
            float lf = bf2float(l);
            unsigned short h2 = f2bf(2.f*hf);
            unsigned short l2 = f2bf(2.f*lf);
            ach[4*d+0]=h2; ach[4*d+1]=h2; ach[4*d+2]=l2; ach[4*d+3]=l2;
            bch[4*d+0]=h;  bch[4*d+1]=l;  bch[4*d+2]=h;  bch[4*d+3]=l;
        }
        unsigned short s1 = f2bf(sq); float s1f = bf2float(s1);
        unsigned short s2 = f2bf(sq - s1f); float s2f = bf2float(s2);
        unsigned short s3 = f2bf(sq - s1f - s2f);
        ach[20] = (unsigned short)(s1 ^ 0x8000u);
        ach[21] = (unsigned short)(s2 ^ 0x8000u);
        ach[22] = (unsigned short)(s3 ^ 0x8000u);
        ach[23] = 0x3F80u; ach[24] = 0x3F80u; ach[25] = 0x3F80u;
        bch[20] = 0x3F80u; bch[21] = 0x3F80u; bch[22] = 0x3F80u;
        bch[23] = (unsigned short)(s1 ^ 0x8000u);
        bch[24] = (unsigned short)(s2 ^ 0x8000u);
        bch[25] = (unsigned short)(s3 ^ 0x8000u);
        #pragma unroll
        for (int k = 26; k < 32; ++k){ ach[k] = 0; bch[k] = 0; }
        #pragma unroll
        for (int ko = 0; ko < 4; ++ko){
            s8v va, vb;
            #pragma unroll
            for (int t = 0; t < 8; ++t){ va[t] = (short)ach[ko*8+t]; vb[t] = (short)bch[ko*8+t]; }
            *(s8v*)(featA_g + ((size_t)ko*NPX + i)*8) = va;
            *(s8v*)(bfrag_g + (size_t)i*32 + ko*8) = vb;
        }
    }

    float u[NC]; float m = -1e30f;
    #pragma unroll
    for (int c = 0; c < NC; ++c){
        float v = ld_in(unary_raw, c*NPX+i, bf);
        v = fminf(fmaxf(v, 1e-5f), 1.0f);
        float lg = logf(v);
        U[c*NPX+i] = lg;
        u[c] = lg;
        m = fmaxf(m, lg);
        if (!use_part) qbf[c*NPX+i] = 0.f;
    }
    float s = 0.f;
    #pragma unroll
    for (int c = 0; c < NC; ++c){ u[c] = expf(u[c]-m); s += u[c]; }
    float inv = 1.f/s;
    #pragma unroll
    for (int c = 0; c < NC; ++c) q[c*NPX+i] = u[c]*inv;
}

// ---------- rowsum of K, 4 j per thread ----------
__global__ __launch_bounds__(256) void rowsum_kernel(const float* __restrict__ feat,
                                                     float* __restrict__ nacc){
    __shared__ __align__(16) float s_feat[RNI*8];
    int tid = threadIdx.x;
    int i0 = blockIdx.y * RNI;
    for (int s = tid; s < RNI*8; s += 256){
        float v = feat[i0*8 + s];
        int sl = s & 7;
        if (sl < 5) v *= 2.0f;
        else if (sl == 5) v = -v;
        s_feat[s] = v;
    }
    __syncthreads();
    int jb0 = blockIdx.x*1024 + tid;
    float4 fj[4]; float fj4[4], nsqj[4];
    float a[4] = {0.f, 0.f, 0.f, 0.f};
    #pragma unroll
    for (int jb = 0; jb < 4; ++jb){
        int j = jb0 + jb*256;
        fj[jb] = *(const float4*)(feat + j*8);
        float2 t = *(const float2*)(feat + j*8 + 4);
        fj4[jb] = t.x; nsqj[jb] = -t.y;
    }
    #pragma unroll 2
    for (int ii = 0; ii < RNI; ++ii){
        const float* sf = s_feat + ii*8;
        float4 f0 = *(const float4*)sf;
        float2 f45 = *(const float2*)(sf+4);
        #pragma unroll
        for (int jb = 0; jb < 4; ++jb){
            float t = nsqj[jb] + f45.y;
            t = fmaf(fj[jb].x, f0.x, t); t = fmaf(fj[jb].y, f0.y, t);
            t = fmaf(fj[jb].z, f0.z, t); t = fmaf(fj[jb].w, f0.w, t);
            t = fmaf(fj4[jb], f45.x, t);
            a[jb] += __builtin_amdgcn_exp2f(t);
        }
    }
    #pragma unroll
    for (int jb = 0; jb < 4; ++jb) atomicAdd(&nacc[jb0 + jb*256], a[jb]);
}

// ---------- normfin + initial tmpA production (iter 0) ----------
__global__ __launch_bounds__(64) void normfin_kernel(const float* __restrict__ nacc,
                                                     float* __restrict__ rnorm,
                                                     const float* __restrict__ q,
                                                     unsigned short* __restrict__ tmpA_g,
                                                     int use_part){
    int j = blockIdx.x*64 + threadIdx.x;
    if (j >= NPX) return;
    float rn = 1.0f / (sqrtf(nacc[j]) + 1e-8f);
    rnorm[j] = rn;
    if (use_part){
        int row = tmp_row(j), idx = tmp_idx(j);
        unsigned short* base = tmpA_g + (size_t)row*256 + idx;
        #pragma unroll
        for (int c = 0; c < NC; ++c)
            base[c*8] = f2bf(q[c*NPX+j] * rn);
        #pragma unroll
        for (int c = NC; c < 32; ++c)
            base[c*8] = 0;
    }
}

// ---------- standalone convs (fallback path only) ----------
__global__ __launch_bounds__(256) void convh_kernel(const float* __restrict__ q,
                                                    float* __restrict__ o){
    int gid = blockIdx.x*256 + threadIdx.x;
    int c   = gid / 2304;
    int rem = gid - c*2304;
    int y   = rem / 24;
    int x0  = (rem - y*24) * 4;
    const float* row = q + c*NPX + y*WW;
    float a0 = 0.f, a1 = 0.f, a2 = 0.f, a3 = 0.f;
    #pragma unroll
    for (int t = 0; t < 52; ++t){
        int xx = x0 + t - RAD2;
        int xc = min(max(xx, 0), WW-1);
        float v = row[xc];
        v = ((unsigned)xx < (unsigned)WW) ? v : 0.f;
        if (t <= 48)           a0 = fmaf(GN[abs(t     - RAD2)], v, a0);
        if (t >= 1 && t <= 49) a1 = fmaf(GN[abs(t - 1 - RAD2)], v, a1);
        if (t >= 2 && t <= 50) a2 = fmaf(GN[abs(t - 2 - RAD2)], v, a2);
        if (t >= 3)            a3 = fmaf(GN[abs(t - 3 - RAD2)], v, a3);
    }
    float* op = o + c*NPX + y*WW + x0;
    op[0] = a0; op[1] = a1; op[2] = a2; op[3] = a3;
}

__global__ __launch_bounds__(256) void convv_kernel(const float* __restrict__ q,
                                                    float* __restrict__ o){
    int gid = blockIdx.x*256 + threadIdx.x;
    int c   = gid / 2304;
    int rem = gid - c*2304;
    int x   = rem % WW;
    int y0  = (rem / WW) * 4;
    const float* col = q + c*NPX + x;
    float a0 = 0.f, a1 = 0.f, a2 = 0.f, a3 = 0.f;
    #pragma unroll
    for (int t = 0; t < 52; ++t){
        int yy = y0 + t - RAD2;
        int yc = min(max(yy, 0), HH-1);
        float v = col[yc*WW];
        v = ((unsigned)yy < (unsigned)HH) ? v : 0.f;
        if (t <= 48)           a0 = fmaf(GN[abs(t     - RAD2)], v, a0);
        if (t >= 1 && t <= 49) a1 = fmaf(GN[abs(t - 1 - RAD2)], v, a1);
        if (t >= 2 && t <= 50) a2 = fmaf(GN[abs(t - 2 - RAD2)], v, a2);
        if (t >= 3)            a3 = fmaf(GN[abs(t - 3 - RAD2)], v, a3);
    }
    float* op = o + c*NPX + x;
    op[(y0+0)*WW] = a0; op[(y0+1)*WW] = a1; op[(y0+2)*WW] = a2; op[(y0+3)*WW] = a3;
}

// ---------- K1 (prestaged + LDS-staged + unrolled): 512-i super-chunk + convv ----------
__global__ __launch_bounds__(256, 2) void k1_pre_kernel(const float* __restrict__ q,
                                                        const unsigned short* __restrict__ featA_g,
                                                        const unsigned short* __restrict__ bfrag_g,
                                                        const unsigned short* __restrict__ tmpA_g,
                                                        float* __restrict__ part,
                                                        float* __restrict__ t1b){
    __shared__ __align__(16) unsigned short s_feat[4*512*8];  // 32 KB: [ko][i_local][8]
    __shared__ __align__(16) unsigned short s_tmp[64*256];    // 32 KB: [row_local][256]
    int tid = threadIdx.x;

    if (blockIdx.x >= K1BIL2){
        // vertical conv FIRST (order swap exact for zero-padded separable conv)
        int gid = (blockIdx.x - K1BIL2)*256 + tid;
        int c   = gid / 2304;
        int rem = gid - c*2304;
        int x   = rem % WW;
        int y0  = (rem / WW) * 4;
        const float* col = q + c*NPX + x;
        float a0 = 0.f, a1 = 0.f, a2 = 0.f, a3 = 0.f;
        #pragma unroll
        for (int t = 0; t < 52; ++t){
            int yy = y0 + t - RAD2;
            int yc = min(max(yy, 0), HH-1);
            float v = col[yc*WW];
            v = ((unsigned)yy < (unsigned)HH) ? v : 0.f;
            if (t <= 48)           a0 = fmaf(GN[abs(t     - RAD2)], v, a0);
            if (t >= 1 && t <= 49) a1 = fmaf(GN[abs(t - 1 - RAD2)], v, a1);
            if (t >= 2 && t <= 50) a2 = fmaf(GN[abs(t - 2 - RAD2)], v, a2);
            if (t >= 3)            a3 = fmaf(GN[abs(t - 3 - RAD2)], v, a3);
        }
        float* op = t1b + c*NPX + x;
        op[(y0+0)*WW] = a0; op[(y0+1)*WW] = a1; op[(y0+2)*WW] = a2; op[(y0+3)*WW] = a3;
        return;
    }

    int jb = blockIdx.x % JBX;
    int chunk = blockIdx.x / JBX;      // 0..17, each covers 512 i
    int i0 = chunk * 512;

    // ---- stage chunk fragments into LDS (pure copy, 64 KB total) ----
    #pragma unroll
    for (int r = 0; r < 8; ++r){
        int e = r*256 + tid;           // 0..2047
        int ko = e >> 9, il = e & 511;
        *(s8v*)(s_feat + (size_t)e*8) =
            *(const s8v*)(featA_g + ((size_t)ko*NPX + i0 + il)*8);
    }
    #pragma unroll
    for (int r = 0; r < 8; ++r){
        int e = r*256 + tid;           // 0..2047
        *(s8v*)(s_tmp + (size_t)e*8) =
            *(const s8v*)(tmpA_g + (size_t)(i0/8)*256 + (size_t)e*8);
    }

    int lane = tid & 63;
    int wv = tid >> 6;
    int half = lane >> 5;
    int jl = lane & 31;
    int jwb = jb*256 + wv*64;

    s8v bf0[NT], bf1[NT];
    #pragma unroll
    for (int n = 0; n < NT; ++n){
        size_t jj = (size_t)(jwb + n*32 + jl)*32;
        bf0[n] = *(const s8v*)(bfrag_g + jj + half*8);
        bf1[n] = *(const s8v*)(bfrag_g + jj + (2+half)*8);
    }

    f16v zf;
    #pragma unroll
    for (int r = 0; r < 16; ++r) zf[r] = 0.f;
    f16v acc[NT];
    #pragma unroll
    for (int n = 0; n < NT; ++n) acc[n] = zf;

    __syncthreads();

    #pragma unroll 4
    for (int b = 0; b < 16; ++b){
        s8v af0 = *(const s8v*)(s_feat + ((size_t)half*512     + b*32 + jl)*8);
        s8v af1 = *(const s8v*)(s_feat + ((size_t)(2+half)*512 + b*32 + jl)*8);
        s8v at0 = *(const s8v*)(s_tmp + (size_t)(b*4 +     half)*256 + jl*8);
        s8v at1 = *(const s8v*)(s_tmp + (size_t)(b*4 + 2 + half)*256 + jl*8);
        #pragma unroll
        for (int n = 0; n < NT; ++n){
            f16v c1 = __builtin_amdgcn_mfma_f32_32x32x16_bf16(af0, bf0[n], zf, 0, 0, 0);
            c1 = __builtin_amdgcn_mfma_f32_32x32x16_bf16(af1, bf1[n], c1, 0, 0, 0);
            union { s8v v; unsigned u[4]; } w1f, w2f;
            #pragma unroll
            for (int p = 0; p < 4; ++p){
                float e0 = __builtin_amdgcn_exp2f(c1[2*p]);
                float e1 = __builtin_amdgcn_exp2f(c1[2*p+1]);
                union { __hip_bfloat162 h2; unsigned uu; } pk;
                pk.h2 = __float22bfloat162_rn(make_float2(e0, e1));
                w1f.u[p] = pk.uu;
                float e2 = __builtin_amdgcn_exp2f(c1[8+2*p]);
                float e3 = __builtin_amdgcn_exp2f(c1[8+2*p+1]);
                pk.h2 = __float22bfloat162_rn(make_float2(e2, e3));
                w2f.u[p] = pk.uu;
            }
            acc[n] = __builtin_amdgcn_mfma_f32_32x32x16_bf16(at0, w1f.v, acc[n], 0, 0, 0);
            acc[n] = __builtin_amdgcn_mfma_f32_32x32x16_bf16(at1, w2f.v, acc[n], 0, 0, 0);
        }
    }
    float* dst = part + (size_t)chunk * (NC*NPX);
    #pragma unroll
    for (int n = 0; n < NT; ++n){
        int j = jwb + n*32 + jl;
        #pragma unroll
        for (int r = 0; r < 16; ++r){
            int c = (r&3) + 8*(r>>2) + 4*half;
            if (c < NC) dst[c*NPX + j] = acc[n][r];
        }
    }
}

// ---------- K1 fallback (atomic path, self-staging, 256-i chunks) ----------
__global__ __launch_bounds__(256, 4) void k1_kernel(const float* __restrict__ q,
                                                    const float* __restrict__ feat,
                                                    const float* __restrict__ rnorm,
                                                    float* __restrict__ qbf){
    __shared__ __align__(16) unsigned short s_featA[4*CH*8];
    __shared__ __align__(16) unsigned short s_tmpA[(CH/8)*TROW];
    int tid = threadIdx.x;
    int jb = blockIdx.x % JBX;
    int chunk = blockIdx.x / JBX;
    int i0 = chunk * CH;

    {
        const float* fp = feat + (size_t)(i0+tid)*8;
        float4 f03 = *(const float4*)fp; float2 f45 = *(const float2*)(fp+4);
        float f[5] = {f03.x, f03.y, f03.z, f03.w, f45.x};
        float sq = f45.y;
        unsigned short ach[32];
        #pragma unroll
        for (int d = 0; d < 5; ++d){
            unsigned short h = f2bf(f[d]);
            float hf = bf2float(h);
            unsigned short l = f2bf(f[d] - hf);
            float lf = bf2float(l);
            unsigned short h2 = f2bf(2.f*hf);
            unsigned short l2 = f2bf(2.f*lf);
            ach[4*d+0]=h2; ach[4*d+1]=h2; ach[4*d+2]=l2; ach[4*d+3]=l2;
        }
        unsigned short s1 = f2bf(sq); float s1f = bf2float(s1);
        unsigned short s2 = f2bf(sq - s1f); float s2f = bf2float(s2);
        unsigned short s3 = f2bf(sq - s1f - s2f);
        ach[20] = (unsigned short)(s1 ^ 0x8000u);
        ach[21] = (unsigned short)(s2 ^ 0x8000u);
        ach[22] = (unsigned short)(s3 ^ 0x8000u);
        ach[23] = 0x3F80u; ach[24] = 0x3F80u; ach[25] = 0x3F80u;
        #pragma unroll
        for (int k = 26; k < 32; ++k) ach[k] = 0;
        #pragma unroll
        for (int ko = 0; ko < 4; ++ko){
            s8v v;
            #pragma unroll
            for (int t = 0; t < 8; ++t) v[t] = (short)ach[ko*8+t];
            *(s8v*)(s_featA + (ko*CH + tid)*8) = v;
        }
    }
    for (int e = tid; e < 32*CH; e += 256){
        int c = e >> 8;
        int i = e & (CH-1);
        float val = (c < NC) ? q[c*NPX + i0 + i] * rnorm[i0 + i] : 0.f;
        int b = i >> 5, L = i & 31;
        int row = b*4 + ((L>>4)&1)*2 + ((L>>2)&1);
        int idx = (L&3) | ((L>>1)&4);
        s_tmpA[row*TROW + c*8 + idx] = f2bf(val);
    }

    int lane = tid & 63;
    int wv = tid >> 6;
    int half = lane >> 5;
    int jl = lane & 31;
    int jwb = jb*256 + wv*64;

    s8v bf0[NT], bf1[NT];
    #pragma unroll
    for (int n = 0; n < NT; ++n){
        const float* fp = feat + (size_t)(jwb + n*32 + jl)*8;
        float4 f03 = *(const float4*)fp; float2 f45 = *(const float2*)(fp+4);
        float f[5] = {f03.x, f03.y, f03.z, f03.w, f45.x};
        float sq = f45.y;
        unsigned short bch[32];
        #pragma unroll
        for (int d = 0; d < 5; ++d){
            unsigned short h = f2bf(f[d]);
            float hf = bf2float(h);
            unsigned short l = f2bf(f[d] - hf);
            bch[4*d+0]=h; bch[4*d+1]=l; bch[4*d+2]=h; bch[4*d+3]=l;
        }
        unsigned short s1 = f2bf(sq); float s1f = bf2float(s1);
        unsigned short s2 = f2bf(sq - s1f); float s2f = bf2float(s2);
        unsigned short s3 = f2bf(sq - s1f - s2f);
        bch[20] = 0x3F80u; bch[21] = 0x3F80u; bch[22] = 0x3F80u;
        bch[23] = (unsigned short)(s1 ^ 0x8000u);
        bch[24] = (unsigned short)(s2 ^ 0x8000u);
        bch[25] = (unsigned short)(s3 ^ 0x8000u);
        #pragma unroll
        for (int k = 26; k < 32; ++k) bch[k] = 0;
        #pragma unroll
        for (int t = 0; t < 8; ++t){
            bf0[n][t] = (short)(half ? bch[8+t]  : bch[t]);
            bf1[n][t] = (short)(half ? bch[24+t] : bch[16+t]);
        }
    }

    f16v zf;
    #pragma unroll
    for (int r = 0; r < 16; ++r) zf[r] = 0.f;
    f16v acc[NT];
    #pragma unroll
    for (int n = 0; n < NT; ++n) acc[n] = zf;

    __syncthreads();

    for (int b = 0; b < 8; ++b){
        s8v af0 = *(const s8v*)(s_featA + (((0+half)*CH + b*32 + jl))*8);
        s8v af1 = *(const s8v*)(s_featA + (((2+half)*CH + b*32 + jl))*8);
        s8v at0 = *(const s8v*)(s_tmpA + (b*4 +     half)*TROW + jl*8);
        s8v at1 = *(const s8v*)(s_tmpA + (b*4 + 2 + half)*TROW + jl*8);
        #pragma unroll
        for (int n = 0; n < NT; ++n){
            f16v c1 = __builtin_amdgcn_mfma_f32_32x32x16_bf16(af0, bf0[n], zf, 0, 0, 0);
            c1 = __builtin_amdgcn_mfma_f32_32x32x16_bf16(af1, bf1[n], c1, 0, 0, 0);
            union { s8v v; unsigned u[4]; } w1f, w2f;
            #pragma unroll
            for (int p = 0; p < 4; ++p){
                float e0 = __builtin_amdgcn_exp2f(c1[2*p]);
                float e1 = __builtin_amdgcn_exp2f(c1[2*p+1]);
                union { __hip_bfloat162 h2; unsigned uu; } pk;
                pk.h2 = __float22bfloat162_rn(make_float2(e0, e1));
                w1f.u[p] = pk.uu;
                float e2 = __builtin_amdgcn_exp2f(c1[8+2*p]);
                float e3 = __builtin_amdgcn_exp2f(c1[8+2*p+1]);
                pk.h2 = __float22bfloat162_rn(make_float2(e2, e3));
                w2f.u[p] = pk.uu;
            }
            acc[n] = __builtin_amdgcn_mfma_f32_32x32x16_bf16(at0, w1f.v, acc[n], 0, 0, 0);
            acc[n] = __builtin_amdgcn_mfma_f32_32x32x16_bf16(at1, w2f.v, acc[n], 0, 0, 0);
        }
    }
    #pragma unroll
    for (int n = 0; n < NT; ++n){
        int j = jwb + n*32 + jl;
        #pragma unroll
        for (int r = 0; r < 16; ++r){
            int c = (r&3) + 8*(r>>2) + 4*half;
            if (c < NC) atomicAdd(&qbf[c*NPX + j], acc[n][r]);
        }
    }
}

// ---------- K2: wide reduce (18 partials) + horizontal conv appended ----------
__global__ __launch_bounds__(256) void k2_kernel(const float* __restrict__ part,
                                                 float* __restrict__ qbf,
                                                 const float* __restrict__ t1b,
                                                 float* __restrict__ qsf){
    int bx = blockIdx.x;
    int tid = threadIdx.x;
    if (bx < RED){
        int idx = bx*256 + tid;
        float s = 0.f;
        #pragma unroll
        for (int ch = 0; ch < NCHK2; ++ch) s += part[(size_t)ch*(NC*NPX) + idx];
        qbf[idx] = s;
        return;
    }
    int gid = (bx - RED)*256 + tid;
    int c   = gid / 2304;
    int rem = gid - c*2304;
    int y   = rem / 24;
    int x0  = (rem - y*24) * 4;
    const float* row = t1b + c*NPX + y*WW;
    float a0 = 0.f, a1 = 0.f, a2 = 0.f, a3 = 0.f;
    #pragma unroll
    for (int t = 0; t < 52; ++t){
        int xx = x0 + t - RAD2;
        int xc = min(max(xx, 0), WW-1);
        float v = row[xc];
        v = ((unsigned)xx < (unsigned)WW) ? v : 0.f;
        if (t <= 48)           a0 = fmaf(GN[abs(t     - RAD2)], v, a0);
        if (t >= 1 && t <= 49) a1 = fmaf(GN[abs(t - 1 - RAD2)], v, a1);
        if (t >= 2 && t <= 50) a2 = fmaf(GN[abs(t - 2 - RAD2)], v, a2);
        if (t >= 3)            a3 = fmaf(GN[abs(t - 3 - RAD2)], v, a3);
    }
    float* op = qsf + c*NPX + y*WW + x0;
    op[0] = a0; op[1] = a1; op[2] = a2; op[3] = a3;
}

// ---------- K3: combine + produce next iteration's tmpA ----------
__global__ __launch_bounds__(64) void combine_kernel(const float* __restrict__ U,
                                                     float* __restrict__ qbf,
                                                     const float* __restrict__ qsf,
                                                     const float* __restrict__ rnorm,
                                                     float* __restrict__ qn,
                                                     unsigned short* __restrict__ tmpA_g,
                                                     void* __restrict__ outp,
                                                     const void* __restrict__ kstd_raw,
                                                     int use_part){
    int j = blockIdx.x*64 + threadIdx.x;
    if (j >= NPX) return;
    float rn = rnorm[j];
    float rn4 = 4.0f * rn;
    float h[NC]; float m = -1e30f;
    #pragma unroll
    for (int c = 0; c < NC; ++c){
        float b = qbf[c*NPX+j];
        if (!use_part) qbf[c*NPX+j] = 0.f;
        float v = U[c*NPX+j] + b*rn4 + 2.0f*qsf[c*NPX+j];
        h[c] = v; m = fmaxf(m, v);
    }
    float s = 0.f;
    #pragma unroll
    for (int c = 0; c < NC; ++c){ h[c] = expf(h[c]-m); s += h[c]; }
    float inv = 1.f/s;
    bool bf = outp ? is_bf16(kstd_raw) : false;
    int row = tmp_row(j), idx = tmp_idx(j);
    unsigned short* base = use_part ? (tmpA_g + (size_t)row*256 + idx) : nullptr;
    #pragma unroll
    for (int c = 0; c < NC; ++c){
        float v = h[c]*inv;
        qn[c*NPX+j] = v;
        if (base) base[c*8] = f2bf(v * rn);
        if (outp){
            if (bf) ((__hip_bfloat16*)outp)[c*NPX+j] = __float2bfloat16(v);
            else    ((float*)outp)[c*NPX+j] = v;
        }
    }
}

extern "C" void kernel_launch(void* const* d_in, const int* in_sizes, int n_in,
                              void* d_out, int out_size, void* d_ws, size_t ws_size,
                              hipStream_t stream) {
    const void* unary_raw = d_in[0];
    const void* ref_raw   = d_in[1];
    const void* kstd_raw  = d_in[2];

    float* w = (float*)d_ws;
    float* feat  = w; w += NPX*8;
    float* U     = w; w += NC*NPX;
    float* qA    = w; w += NC*NPX;
    float* qB    = w; w += NC*NPX;
    float* t1b   = w; w += NC*NPX;
    float* qsf   = w; w += NC*NPX;
    float* qbf   = w; w += NC*NPX;
    float* nacc  = w; w += NPX;
    float* rnorm = w; w += NPX;
    unsigned short* featA_g = (unsigned short*)w; w += (size_t)4*NPX*8/2;
    unsigned short* bfrag_g = (unsigned short*)w; w += (size_t)NPX*32/2;
    unsigned short* tmpA_g  = (unsigned short*)w; w += (size_t)(NPX/8)*256/2;
    float* part  = w; w += (size_t)NCHK2*NC*NPX;

    size_t need = (size_t)((char*)w - (char*)d_ws);
    int use_part = (ws_size >= need) ? 1 : 0;

    hipLaunchKernelGGL(setup_kernel, dim3(144), dim3(64), 0, stream,
                       unary_raw, ref_raw, kstd_raw, feat, U, qA, qbf, nacc,
                       featA_g, bfrag_g, use_part);
    hipLaunchKernelGGL(rowsum_kernel, dim3(9, RCH), dim3(256), 0, stream, feat, nacc);
    hipLaunchKernelGGL(normfin_kernel, dim3(144), dim3(64), 0, stream,
                       nacc, rnorm, qA, tmpA_g, use_part);

    float* qc = qA; float* qn = qB;
    for (int it = 0; it < 5; ++it){
        if (use_part){
            hipLaunchKernelGGL(k1_pre_kernel, dim3(K1BIL2 + CVBLK), dim3(256), 0, stream,
                               qc, featA_g, bfrag_g, tmpA_g, part, t1b);
            hipLaunchKernelGGL(k2_kernel, dim3(RED + CVBLK), dim3(256), 0, stream,
                               part, qbf, t1b, qsf);
        } else {
            hipLaunchKernelGGL(convh_kernel, dim3(189), dim3(256), 0, stream, qc, t1b);
            hipLaunchKernelGGL(convv_kernel, dim3(189), dim3(256), 0, stream, t1b, qsf);
            hipLaunchKernelGGL(k1_kernel, dim3(JBX*NCHK), dim3(256), 0, stream,
                               qc, feat, rnorm, qbf);
        }
        hipLaunchKernelGGL(combine_kernel, dim3(144), dim3(64), 0, stream,
                           U, qbf, qsf, rnorm, qn, tmpA_g,
                           (it == 4) ? d_out : (void*)nullptr, kstd_raw, use_part);
        float* tswap = qc; qc = qn; qn = tswap;
    }
}